// Round 2
// baseline (104.425 us; speedup 1.0000x reference)
//
#include <hip/hip_runtime.h>

#define TPB 256
#define ROWS_W 64                    // rows per wave-tile
#define TILE_F (ROWS_W * 25)         // 1600 floats per array per tile
#define TILE_F4 (TILE_F / 4)         // 400 float4 per array per tile
#define WAVE_LDS_F (2 * TILE_F)      // pre + tar per wave = 3200 floats (12.8 KB)
#define NLD 7                        // ceil(400/64) float4 loads per lane per array

// stable rank of 4 values (tie-break: lower index first) — matches jnp stable argsort
__device__ __forceinline__ void rank4(const float v[4], int r[4]) {
#pragma unroll
    for (int i = 0; i < 4; ++i) {
        int rk = 0;
#pragma unroll
        for (int j = 0; j < 4; ++j)
            rk += (v[j] < v[i] || (v[j] == v[i] && j < i)) ? 1 : 0;
        r[i] = rk;
    }
}

__device__ __forceinline__ void judge_group(const float* __restrict__ p,
                                            const float* __restrict__ t,
                                            int& calc, int& acc) {
    const float ERRv = 0.09f;   // 3 * 0.03
    const float GAPv = 0.03f;   // 3 * 0.01
    float p0 = p[0], p1 = p[1], p2 = p[2], p3 = p[3];
    float t0 = t[0], t1 = t[1], t2 = t[2], t3 = t[3];

    // out = 3 * softmax(p)
    float m  = fmaxf(fmaxf(p0, p1), fmaxf(p2, p3));
    float e0 = __expf(p0 - m), e1 = __expf(p1 - m);
    float e2 = __expf(p2 - m), e3 = __expf(p3 - m);
    float inv = 3.0f / (e0 + e1 + e2 + e3);
    float o0 = e0 * inv, o1 = e1 * inv, o2 = e2 * inv, o3 = e3 * inv;

    bool within = fabsf(o0 - t0) <= ERRv && fabsf(o1 - t1) <= ERRv &&
                  fabsf(o2 - t2) <= ERRv && fabsf(o3 - t3) <= ERRv;

    // sorted target values (ascending): need st0, st1, st2
    float l01 = fminf(t0, t1), h01 = fmaxf(t0, t1);
    float l23 = fminf(t2, t3), h23 = fmaxf(t2, t3);
    float st0 = fminf(l01, l23), mlo = fmaxf(l01, l23);
    float mhi = fminf(h01, h23);
    float st1 = fminf(mlo, mhi), st2 = fmaxf(mlo, mhi);
    float d1 = st1 - st0;
    float d2 = st2 - st1;

    float ov[4] = {o0, o1, o2, o3};
    float tv[4] = {t0, t1, t2, t3};
    int ro[4], rt[4];
    rank4(ov, ro);
    rank4(tv, rt);

    bool jump = within && (
        (d1 < GAPv && d2 < GAPv) ||
        (d1 < GAPv && ro[2] == rt[2]) ||
        (d2 < GAPv && ro[0] == rt[0]));

    int nz = (t0 == 0.0f) + (t1 == 0.0f) + (t2 == 0.0f) + (t3 == 0.0f);
    bool match_all = (ro[0] == rt[0]) && (ro[1] == rt[1]) &&
                     (ro[2] == rt[2]) && (ro[3] == rt[3]);

    int tago2 = 0, tago3 = 0, tagt2 = 0, tagt3 = 0;
#pragma unroll
    for (int i = 0; i < 4; ++i) {
        if (ro[i] == 2) tago2 = i;
        if (ro[i] == 3) tago3 = i;
        if (rt[i] == 2) tagt2 = i;
        if (rt[i] == 3) tagt3 = i;
    }

    bool c_lt2 = !jump && (nz < 2);
    bool c_eq2 = !jump && (nz == 2) && (tago2 == tagt2) && (tago3 == tagt3);
    bool c_eq3 = !jump && (nz == 3) && (ro[3] == 3);

    calc += (jump || c_lt2 || c_eq2 || c_eq3) ? 1 : 0;
    acc  += (jump || (c_lt2 && match_all) || c_eq2 || c_eq3) ? 1 : 0;
}

__global__ __launch_bounds__(TPB, 3)
void recall_main_kernel(const float* __restrict__ pre,
                        const float* __restrict__ tar,
                        float* __restrict__ partial,
                        int B, int ntiles, int nwaves) {
    // per-wave private LDS: no inter-wave sharing, no __syncthreads in main loop
    __shared__ float s_data[(TPB / 64) * WAVE_LDS_F];   // 51.2 KB
    __shared__ float s_red[8];

    const int t    = threadIdx.x;
    const int lane = t & 63;
    const int wid  = t >> 6;
    const int W    = blockIdx.x * (TPB / 64) + wid;     // global wave id
    const int total4 = (B * 25) >> 2;

    const float4* pre4 = (const float4*)pre;
    const float4* tar4 = (const float4*)tar;

    float* s_pre = s_data + wid * WAVE_LDS_F;           // 1600 floats
    float* s_tar = s_pre + TILE_F;                      // 1600 floats
    float4* sp4 = (float4*)s_pre;
    float4* st4 = (float4*)s_tar;

    float csum = 0.0f, vsum = 0.0f;

    float4 ra[NLD], rb[NLD];
    int tile = W;
    bool valid = tile < ntiles;

    // prologue: issue loads for first tile
    if (valid) {
        const int gbase = tile * TILE_F4;
#pragma unroll
        for (int k = 0; k < NLD; ++k) {
            int idx = k * 64 + lane;
            if (idx < TILE_F4) {
                int gi = gbase + idx;
                if (gi < total4) { ra[k] = pre4[gi]; rb[k] = tar4[gi]; }
            }
        }
    }

    while (valid) {
        const int next = tile + nwaves;
        const bool nvalid = next < ntiles;

        // stage current tile regs -> my wave's LDS (compiler waits vmcnt here)
#pragma unroll
        for (int k = 0; k < NLD; ++k) {
            int idx = k * 64 + lane;
            if (idx < TILE_F4) { sp4[idx] = ra[k]; st4[idx] = rb[k]; }
        }

        // issue next tile's loads; they fly during compute below
        if (nvalid) {
            const int gbase = next * TILE_F4;
#pragma unroll
            for (int k = 0; k < NLD; ++k) {
                int idx = k * 64 + lane;
                if (idx < TILE_F4) {
                    int gi = gbase + idx;
                    if (gi < total4) { ra[k] = pre4[gi]; rb[k] = tar4[gi]; }
                }
            }
        }

        // wave-internal cross-lane LDS dependency: drain DS queue before reads
        asm volatile("s_waitcnt lgkmcnt(0)" ::: "memory");

        const int row = tile * ROWS_W + lane;
        if (row < B) {
            const float* rp = s_pre + lane * 25;
            const float* rt = s_tar + lane * 25;
            int calc = 0, acc = 0;
#pragma unroll
            for (int g = 0; g < 6; ++g)
                judge_group(rp + g * 4, rt + g * 4, calc, acc);
            if (calc > 0) {
                csum += __fdividef((float)acc, (float)calc);
                vsum += 1.0f;
            }
        }

        tile = next;
        valid = nvalid;
    }

    // deterministic block reduction
#pragma unroll
    for (int off = 32; off > 0; off >>= 1) {
        csum += __shfl_down(csum, off);
        vsum += __shfl_down(vsum, off);
    }
    if (lane == 0) { s_red[wid] = csum; s_red[4 + wid] = vsum; }
    __syncthreads();
    if (t == 0) {
        float c = s_red[0] + s_red[1] + s_red[2] + s_red[3];
        float v = s_red[4] + s_red[5] + s_red[6] + s_red[7];
        partial[2 * blockIdx.x]     = c;
        partial[2 * blockIdx.x + 1] = v;
    }
}

__global__ __launch_bounds__(TPB)
void recall_finalize_kernel(const float* __restrict__ partial, int n,
                            float* __restrict__ out) {
    __shared__ float s_red[8];
    float c = 0.0f, v = 0.0f;
    for (int i = threadIdx.x; i < n; i += TPB) {
        c += partial[2 * i];
        v += partial[2 * i + 1];
    }
#pragma unroll
    for (int off = 32; off > 0; off >>= 1) {
        c += __shfl_down(c, off);
        v += __shfl_down(v, off);
    }
    int wave = threadIdx.x >> 6;
    if ((threadIdx.x & 63) == 0) { s_red[wave] = c; s_red[4 + wave] = v; }
    __syncthreads();
    if (threadIdx.x == 0) {
        float cs = s_red[0] + s_red[1] + s_red[2] + s_red[3];
        float vs = s_red[4] + s_red[5] + s_red[6] + s_red[7];
        out[0] = (vs > 0.0f) ? (cs / vs) : 0.0f;
    }
}

extern "C" void kernel_launch(void* const* d_in, const int* in_sizes, int n_in,
                              void* d_out, int out_size, void* d_ws, size_t ws_size,
                              hipStream_t stream) {
    const float* pre = (const float*)d_in[0];
    const float* tar = (const float*)d_in[1];
    float* out = (float*)d_out;
    float* partial = (float*)d_ws;

    int B = in_sizes[0] / 25;
    int ntiles = (B + ROWS_W - 1) / ROWS_W;

    // exact residency: 3 blocks/CU (51.2 KB LDS) x 256 CU = 768 blocks
    int grid = 768;
    if (grid > ntiles) grid = ntiles;
    if (grid < 1) grid = 1;
    int nwaves = grid * (TPB / 64);

    recall_main_kernel<<<grid, TPB, 0, stream>>>(pre, tar, partial, B, ntiles, nwaves);
    recall_finalize_kernel<<<1, TPB, 0, stream>>>(partial, grid, out);
}

// Round 3
// 62.746 us; speedup vs baseline: 1.6642x; 1.6642x over previous
//
#include <hip/hip_runtime.h>
#include <stdint.h>

#define TPB 128                      // 2 waves per block
#define TILE_ROWS 64                 // rows per wave-tile
#define TILE_F4A 400                 // float4 per array per tile (64*25/4)
#define TILE_F4  800                 // float4 per tile, both arrays
#define TILE_FLOATS 3200             // floats per tile (pre 1600 + tar 1600)
#define WAVE_LDS_FLOATS (2 * TILE_FLOATS)   // double buffer = 25.6 KB per wave
#define NISSUE 13                    // ceil(800/64) global_load_lds per tile per wave

typedef __attribute__((address_space(3))) uint32_t lds_u32;
typedef const __attribute__((address_space(1))) uint32_t glob_u32;

// stable rank of 4 values (tie-break: lower index first) — matches jnp stable argsort
__device__ __forceinline__ void rank4(const float v[4], int r[4]) {
#pragma unroll
    for (int i = 0; i < 4; ++i) {
        int rk = 0;
#pragma unroll
        for (int j = 0; j < 4; ++j)
            rk += (v[j] < v[i] || (v[j] == v[i] && j < i)) ? 1 : 0;
        r[i] = rk;
    }
}

__device__ __forceinline__ void judge_group(const float* __restrict__ p,
                                            const float* __restrict__ t,
                                            int& calc, int& acc) {
    const float ERRv = 0.09f;   // 3 * 0.03
    const float GAPv = 0.03f;   // 3 * 0.01
    float p0 = p[0], p1 = p[1], p2 = p[2], p3 = p[3];
    float t0 = t[0], t1 = t[1], t2 = t[2], t3 = t[3];

    // out = 3 * softmax(p)
    float m  = fmaxf(fmaxf(p0, p1), fmaxf(p2, p3));
    float e0 = __expf(p0 - m), e1 = __expf(p1 - m);
    float e2 = __expf(p2 - m), e3 = __expf(p3 - m);
    float inv = 3.0f / (e0 + e1 + e2 + e3);
    float o0 = e0 * inv, o1 = e1 * inv, o2 = e2 * inv, o3 = e3 * inv;

    bool within = fabsf(o0 - t0) <= ERRv && fabsf(o1 - t1) <= ERRv &&
                  fabsf(o2 - t2) <= ERRv && fabsf(o3 - t3) <= ERRv;

    // sorted target values (ascending): need st0, st1, st2
    float l01 = fminf(t0, t1), h01 = fmaxf(t0, t1);
    float l23 = fminf(t2, t3), h23 = fmaxf(t2, t3);
    float st0 = fminf(l01, l23), mlo = fmaxf(l01, l23);
    float mhi = fminf(h01, h23);
    float st1 = fminf(mlo, mhi), st2 = fmaxf(mlo, mhi);
    float d1 = st1 - st0;
    float d2 = st2 - st1;

    float ov[4] = {o0, o1, o2, o3};
    float tv[4] = {t0, t1, t2, t3};
    int ro[4], rt[4];
    rank4(ov, ro);
    rank4(tv, rt);

    bool jump = within && (
        (d1 < GAPv && d2 < GAPv) ||
        (d1 < GAPv && ro[2] == rt[2]) ||
        (d2 < GAPv && ro[0] == rt[0]));

    int nz = (t0 == 0.0f) + (t1 == 0.0f) + (t2 == 0.0f) + (t3 == 0.0f);
    bool match_all = (ro[0] == rt[0]) && (ro[1] == rt[1]) &&
                     (ro[2] == rt[2]) && (ro[3] == rt[3]);

    int tago2 = 0, tago3 = 0, tagt2 = 0, tagt3 = 0;
#pragma unroll
    for (int i = 0; i < 4; ++i) {
        if (ro[i] == 2) tago2 = i;
        if (ro[i] == 3) tago3 = i;
        if (rt[i] == 2) tagt2 = i;
        if (rt[i] == 3) tagt3 = i;
    }

    bool c_lt2 = !jump && (nz < 2);
    bool c_eq2 = !jump && (nz == 2) && (tago2 == tagt2) && (tago3 == tagt3);
    bool c_eq3 = !jump && (nz == 3) && (ro[3] == 3);

    calc += (jump || c_lt2 || c_eq2 || c_eq3) ? 1 : 0;
    acc  += (jump || (c_lt2 && match_all) || c_eq2 || c_eq3) ? 1 : 0;
}

// stage one 64-row tile (pre||tar, 12800 B) into `buf` via global_load_lds.
// LDS dest is linear: issue k covers bytes [k*1024, k*1024+active*16).
// Exactly NISSUE=13 vmem instructions per call (k=12 runs with 32 active lanes).
__device__ __forceinline__ void stage_tile(const float4* __restrict__ pre4,
                                           const float4* __restrict__ tar4,
                                           int tile, int total4a,
                                           float* buf, int lane) {
#pragma unroll
    for (int k = 0; k < NISSUE; ++k) {
        int f4 = k * 64 + lane;
        if (f4 < TILE_F4) {
            int ia = (f4 < TILE_F4A) ? (tile * TILE_F4A + f4)
                                     : (tile * TILE_F4A + f4 - TILE_F4A);
            if (ia >= total4a) ia = total4a - 1;           // clamp (tail safety)
            const float4* src = (f4 < TILE_F4A) ? (pre4 + ia) : (tar4 + ia);
            __builtin_amdgcn_global_load_lds((glob_u32*)(const void*)src,
                                             (lds_u32*)(void*)(buf + k * 256),
                                             16, 0, 0);
        }
    }
}

__device__ __forceinline__ void compute_tile(const float* __restrict__ buf,
                                             int tile, int B, int lane,
                                             float& csum, float& vsum) {
    int row = tile * TILE_ROWS + lane;
    if (row < B) {
        const float* rp = buf + lane * 25;          // pre rows: floats [0,1600)
        const float* rt = buf + 1600 + lane * 25;   // tar rows: floats [1600,3200)
        int calc = 0, acc = 0;
#pragma unroll
        for (int g = 0; g < 6; ++g)
            judge_group(rp + g * 4, rt + g * 4, calc, acc);
        if (calc > 0) {
            csum += __fdividef((float)acc, (float)calc);
            vsum += 1.0f;
        }
    }
}

__global__ __launch_bounds__(TPB)
void recall_main_kernel(const float* __restrict__ pre,
                        const float* __restrict__ tar,
                        float* __restrict__ partial,
                        int B, int ntiles, int nwaves) {
    __shared__ __align__(16) float s_data[(TPB / 64) * WAVE_LDS_FLOATS]; // 51.2 KB

    const int t    = threadIdx.x;
    const int lane = t & 63;
    const int wid  = t >> 6;
    const int W    = blockIdx.x * (TPB / 64) + wid;   // global wave id
    const int total4a = (B * 25) >> 2;                // float4 count per array

    const float4* pre4 = (const float4*)pre;
    const float4* tar4 = (const float4*)tar;

    float* wbase = s_data + wid * WAVE_LDS_FLOATS;    // this wave's 25.6 KB

    float csum = 0.0f, vsum = 0.0f;

    int tile = W;
    int cur = 0;
    if (tile < ntiles)
        stage_tile(pre4, tar4, tile, total4a, wbase, lane);   // prologue

    while (tile < ntiles) {
        const int next = tile + nwaves;
        const bool has_next = next < ntiles;

        asm volatile("" ::: "memory");   // keep prior LDS reads before next stage
        if (has_next)
            stage_tile(pre4, tar4, next, total4a,
                       wbase + (cur ^ 1) * TILE_FLOATS, lane);

        // wait for CURRENT tile's 13 loads; leave next tile's 13 in flight
        if (has_next) asm volatile("s_waitcnt vmcnt(13)" ::: "memory");
        else          asm volatile("s_waitcnt vmcnt(0)"  ::: "memory");

        compute_tile(wbase + cur * TILE_FLOATS, tile, B, lane, csum, vsum);

        cur ^= 1;
        tile = next;
    }

    // per-wave reduction; each wave writes its own partial slot (no barrier)
#pragma unroll
    for (int off = 32; off > 0; off >>= 1) {
        csum += __shfl_down(csum, off);
        vsum += __shfl_down(vsum, off);
    }
    if (lane == 0) {
        partial[2 * W]     = csum;
        partial[2 * W + 1] = vsum;
    }
}

__global__ __launch_bounds__(256)
void recall_finalize_kernel(const float* __restrict__ partial, int n,
                            float* __restrict__ out) {
    __shared__ float s_red[8];
    float c = 0.0f, v = 0.0f;
    for (int i = threadIdx.x; i < n; i += 256) {
        c += partial[2 * i];
        v += partial[2 * i + 1];
    }
#pragma unroll
    for (int off = 32; off > 0; off >>= 1) {
        c += __shfl_down(c, off);
        v += __shfl_down(v, off);
    }
    int wave = threadIdx.x >> 6;
    if ((threadIdx.x & 63) == 0) { s_red[wave] = c; s_red[4 + wave] = v; }
    __syncthreads();
    if (threadIdx.x == 0) {
        float cs = s_red[0] + s_red[1] + s_red[2] + s_red[3];
        float vs = s_red[4] + s_red[5] + s_red[6] + s_red[7];
        out[0] = (vs > 0.0f) ? (cs / vs) : 0.0f;
    }
}

extern "C" void kernel_launch(void* const* d_in, const int* in_sizes, int n_in,
                              void* d_out, int out_size, void* d_ws, size_t ws_size,
                              hipStream_t stream) {
    const float* pre = (const float*)d_in[0];
    const float* tar = (const float*)d_in[1];
    float* out = (float*)d_out;
    float* partial = (float*)d_ws;

    int B = in_sizes[0] / 25;
    int ntiles = (B + TILE_ROWS - 1) / TILE_ROWS;

    // 3 blocks/CU (51.2 KB LDS each) x 256 CU = 768 blocks, 1536 waves
    int grid = 768;
    if (grid > ntiles) grid = ntiles;
    if (grid < 1) grid = 1;
    int nwaves = grid * (TPB / 64);

    recall_main_kernel<<<grid, TPB, 0, stream>>>(pre, tar, partial, B, ntiles, nwaves);
    recall_finalize_kernel<<<1, 256, 0, stream>>>(partial, nwaves, out);
}

// Round 4
// 49.340 us; speedup vs baseline: 2.1165x; 1.2717x over previous
//
#include <hip/hip_runtime.h>

#define TPB 256
#define CHUNK_ROWS 256
#define ROW_F 25
#define CHUNK_F (CHUNK_ROWS * ROW_F)   // 6400 floats per array per chunk
#define CHUNK_F4 (CHUNK_F / 4)         // 1600 float4 per array per chunk

// Slim judge: ranks of out == ranks of pre (softmax monotone); "within" in
// scaled form |3*e_i - t_i*S| <= 0.09*S (no divide on the critical chain).
__device__ __forceinline__ void judge_group(const float* __restrict__ p,
                                            const float* __restrict__ t,
                                            int& calc, int& acc) {
    const float GAPv = 0.03f;   // 3 * 0.01
    float p0 = p[0], p1 = p[1], p2 = p[2], p3 = p[3];
    float t0 = t[0], t1 = t[1], t2 = t[2], t3 = t[3];

    float m  = fmaxf(fmaxf(p0, p1), fmaxf(p2, p3));
    float e0 = __expf(p0 - m), e1 = __expf(p1 - m);
    float e2 = __expf(p2 - m), e3 = __expf(p3 - m);
    float S  = (e0 + e1) + (e2 + e3);
    float thr = 0.09f * S;
    float w0 = fmaf(3.0f, e0, -t0 * S);
    float w1 = fmaf(3.0f, e1, -t1 * S);
    float w2 = fmaf(3.0f, e2, -t2 * S);
    float w3 = fmaf(3.0f, e3, -t3 * S);
    bool within = fabsf(w0) <= thr && fabsf(w1) <= thr &&
                  fabsf(w2) <= thr && fabsf(w3) <= thr;

    // stable ranks of p (== ranks of out). g_ij = (p_j < p_i), i<j.
    int g01 = p1 < p0, g02 = p2 < p0, g03 = p3 < p0;
    int g12 = p2 < p1, g13 = p3 < p1, g23 = p3 < p2;
    int ro0 = g01 + g02 + g03;
    int ro1 = 1 - g01 + g12 + g13;
    int ro2 = 2 - g02 - g12 + g23;
    int ro3 = 3 - g03 - g13 - g23;

    int h01 = t1 < t0, h02 = t2 < t0, h03 = t3 < t0;
    int h12 = t2 < t1, h13 = t3 < t1, h23 = t3 < t2;
    int rt0 = h01 + h02 + h03;
    int rt1 = 1 - h01 + h12 + h13;
    int rt2 = 2 - h02 - h12 + h23;
    int rt3 = 3 - h03 - h13 - h23;

    // sorted target values (ascending): st0 <= st1 <= st2
    float l01 = fminf(t0, t1), x01 = fmaxf(t0, t1);
    float l23 = fminf(t2, t3), x23 = fmaxf(t2, t3);
    float st0 = fminf(l01, l23), mlo = fmaxf(l01, l23);
    float mhi = fminf(x01, x23);
    float st1 = fminf(mlo, mhi), st2 = fmaxf(mlo, mhi);
    float d1 = st1 - st0;
    float d2 = st2 - st1;

    bool jump = within && (
        ((d1 < GAPv) & (d2 < GAPv)) ||
        ((d1 < GAPv) & (ro2 == rt2)) ||
        ((d2 < GAPv) & (ro0 == rt0)));

    int nz = (t0 == 0.0f) + (t1 == 0.0f) + (t2 == 0.0f) + (t3 == 0.0f);
    bool match_all = (ro0 == rt0) & (ro1 == rt1) & (ro2 == rt2) & (ro3 == rt3);

    // tagout[k]==tagtar[k]  <=>  some index i has ro_i==k and rt_i==k
    bool s2 = ((ro0 == 2) & (rt0 == 2)) | ((ro1 == 2) & (rt1 == 2)) |
              ((ro2 == 2) & (rt2 == 2)) | ((ro3 == 2) & (rt3 == 2));
    bool s3 = ((ro0 == 3) & (rt0 == 3)) | ((ro1 == 3) & (rt1 == 3)) |
              ((ro2 == 3) & (rt2 == 3)) | ((ro3 == 3) & (rt3 == 3));

    bool c_lt2 = !jump & (nz < 2);
    bool c_eq2 = !jump & (nz == 2) & s2 & s3;
    bool c_eq3 = !jump & (nz == 3) & (ro3 == 3);

    calc += (jump | c_lt2 | c_eq2 | c_eq3) ? 1 : 0;
    acc  += (jump | (c_lt2 & match_all) | c_eq2 | c_eq3) ? 1 : 0;
}

__global__ __launch_bounds__(TPB, 6)
void recall_main_kernel(const float* __restrict__ pre,
                        const float* __restrict__ tar,
                        float* __restrict__ partial,
                        int B, int nchunks) {
    __shared__ __align__(16) float s_pre[CHUNK_F];
    __shared__ __align__(16) float s_tar[CHUNK_F];
    __shared__ float s_red[8];

    const int t = threadIdx.x;
    const int total  = B * ROW_F;
    const int total4 = total >> 2;

    const float4* pre4 = (const float4*)pre;
    const float4* tar4 = (const float4*)tar;
    float4* sp4 = (float4*)s_pre;
    float4* st4 = (float4*)s_tar;

    float csum = 0.0f, vsum = 0.0f;

    for (int chunk = blockIdx.x; chunk < nchunks; chunk += gridDim.x) {
        __syncthreads();   // previous iteration's LDS reads done before overwrite

        const int base  = chunk * CHUNK_F;
        const int base4 = chunk * CHUNK_F4;

#pragma unroll
        for (int k = 0; k < 7; ++k) {
            int li = t + k * TPB;
            if (li < CHUNK_F4) {
                int gi = base4 + li;
                if (gi < total4) {
                    sp4[li] = pre4[gi];
                    st4[li] = tar4[gi];
                }
            }
        }
        // scalar tail (only if total % 4 != 0 and this chunk owns it)
        if (base + CHUNK_F > (total4 << 2)) {
            for (int li = t; li < CHUNK_F; li += TPB) {
                int gi = base + li;
                if (gi >= (total4 << 2) && gi < total) {
                    s_pre[li] = pre[gi];
                    s_tar[li] = tar[gi];
                }
            }
        }
        __syncthreads();

        int row = chunk * CHUNK_ROWS + t;
        if (row < B) {
            const float* rp = &s_pre[t * ROW_F];
            const float* rt = &s_tar[t * ROW_F];
            int calc = 0, acc = 0;
#pragma unroll
            for (int g = 0; g < 6; ++g)
                judge_group(rp + g * 4, rt + g * 4, calc, acc);
            if (calc > 0) {
                csum += __fdividef((float)acc, (float)calc);
                vsum += 1.0f;
            }
        }
    }

    // deterministic block reduction
#pragma unroll
    for (int off = 32; off > 0; off >>= 1) {
        csum += __shfl_down(csum, off);
        vsum += __shfl_down(vsum, off);
    }
    int wave = t >> 6;
    if ((t & 63) == 0) { s_red[wave] = csum; s_red[4 + wave] = vsum; }
    __syncthreads();
    if (t == 0) {
        float c = s_red[0] + s_red[1] + s_red[2] + s_red[3];
        float v = s_red[4] + s_red[5] + s_red[6] + s_red[7];
        partial[2 * blockIdx.x]     = c;
        partial[2 * blockIdx.x + 1] = v;
    }
}

__global__ __launch_bounds__(TPB)
void recall_finalize_kernel(const float* __restrict__ partial, int n,
                            float* __restrict__ out) {
    __shared__ float s_red[8];
    float c = 0.0f, v = 0.0f;
    for (int i = threadIdx.x; i < n; i += TPB) {
        c += partial[2 * i];
        v += partial[2 * i + 1];
    }
#pragma unroll
    for (int off = 32; off > 0; off >>= 1) {
        c += __shfl_down(c, off);
        v += __shfl_down(v, off);
    }
    int wave = threadIdx.x >> 6;
    if ((threadIdx.x & 63) == 0) { s_red[wave] = c; s_red[4 + wave] = v; }
    __syncthreads();
    if (threadIdx.x == 0) {
        float cs = s_red[0] + s_red[1] + s_red[2] + s_red[3];
        float vs = s_red[4] + s_red[5] + s_red[6] + s_red[7];
        out[0] = (vs > 0.0f) ? (cs / vs) : 0.0f;
    }
}

extern "C" void kernel_launch(void* const* d_in, const int* in_sizes, int n_in,
                              void* d_out, int out_size, void* d_ws, size_t ws_size,
                              hipStream_t stream) {
    const float* pre = (const float*)d_in[0];
    const float* tar = (const float*)d_in[1];
    float* out = (float*)d_out;
    float* partial = (float*)d_ws;

    int B = in_sizes[0] / ROW_F;
    int nchunks = (B + CHUNK_ROWS - 1) / CHUNK_ROWS;

    // 6 blocks/CU (25.6 KB LDS each) x 256 CU = 1536 blocks, exactly resident
    int grid = 1536;
    if (grid > nchunks) grid = nchunks;
    if (grid < 1) grid = 1;

    recall_main_kernel<<<grid, TPB, 0, stream>>>(pre, tar, partial, B, nchunks);
    recall_finalize_kernel<<<1, TPB, 0, stream>>>(partial, grid, out);
}